// Round 11
// baseline (9574.233 us; speedup 1.0000x reference)
//
#include <hip/hip_runtime.h>
#include <hip/hip_bf16.h>

#define L   2304
#define D   256
#define NHD 8
#define HD  32
#define FF  1024
#define HH  48
#define WWW 48

// Diagnostic: fill output with a constant (decodable from reported absmax).
__global__ __launch_bounds__(256) void diag_kernel(float* __restrict__ out, float c, int n)
{
    int i = blockIdx.x * 256 + threadIdx.x;
    if (i < n) out[i] = c;
}

// ---------------------------------------------------------------------------
// LayerNorm over D=256, fp32. One block per row; tree reduction.
// ---------------------------------------------------------------------------
__global__ __launch_bounds__(256) void ln_kernel(
    const float* __restrict__ inA, const float* __restrict__ inB,
    const float* __restrict__ g, const float* __restrict__ b,
    float* __restrict__ out)
{
    int row = blockIdx.x, t = threadIdx.x;
    size_t idx = (size_t)row * D + t;
    float v = inA[idx];
    if (inB) v += inB[idx];
    __shared__ float rs[256], rq[256];
    rs[t] = v; rq[t] = v * v;
    __syncthreads();
    for (int o = 128; o > 0; o >>= 1) {
        if (t < o) { rs[t] += rs[t + o]; rq[t] += rq[t + o]; }
        __syncthreads();
    }
    float mean = rs[0] * (1.f / D);
    float var  = rq[0] * (1.f / D) - mean * mean;
    float rstd = rsqrtf(var + 1e-5f);
    out[idx] = (v - mean) * rstd * g[t] + b[t];
}

// ---------------------------------------------------------------------------
// Naive GEMM: C[M,N] = A[M,K] @ W[N,K]^T + bias (+res). One thread/output.
// res may alias out (each thread touches only its own idx).
// ---------------------------------------------------------------------------
__global__ __launch_bounds__(256) void gemm_naive(
    const float* __restrict__ A, const float* __restrict__ W,
    const float* __restrict__ bias, const float* res, float* out,
    int M, int N, int K)
{
    int c = blockIdx.y * 16 + threadIdx.x;
    int r = blockIdx.x * 16 + threadIdx.y;
    if (r >= M || c >= N) return;
    const float* a = A + (size_t)r * K;
    const float* w = W + (size_t)c * K;
    float acc = 0.f;
    for (int k = 0; k < K; k++) acc += a[k] * w[k];
    acc += bias[c];
    size_t idx = (size_t)r * N + c;
    if (res) acc += res[idx];
    out[idx] = acc;
}

// ---------------------------------------------------------------------------
// Naive attention: one block (256 thr) per (query l, head h). fp32.
// ---------------------------------------------------------------------------
__global__ __launch_bounds__(256) void attn_naive(
    const float* __restrict__ Q, const float* __restrict__ K,
    const float* __restrict__ V, float* __restrict__ O,
    int Lk, float scale)
{
    extern __shared__ float sc[];
    __shared__ float red[256];
    __shared__ float vout[8][HD];
    int l = blockIdx.x, h = blockIdx.y, t = threadIdx.x;
    const float* qp = Q + (size_t)l * D + h * HD;
    float qv[HD];
    #pragma unroll
    for (int i = 0; i < HD; i++) qv[i] = qp[i] * scale;

    float lm = -1e30f;
    for (int j = t; j < Lk; j += 256) {
        const float* kp = K + (size_t)j * D + h * HD;
        float s = 0.f;
        #pragma unroll
        for (int i = 0; i < HD; i++) s += qv[i] * kp[i];
        sc[j] = s;
        lm = fmaxf(lm, s);
    }
    red[t] = lm;
    __syncthreads();
    for (int o = 128; o > 0; o >>= 1) {
        if (t < o) red[t] = fmaxf(red[t], red[t + o]);
        __syncthreads();
    }
    float mx = red[0];
    __syncthreads();

    float ls = 0.f;
    for (int j = t; j < Lk; j += 256) {
        float e = __expf(sc[j] - mx);
        sc[j] = e;
        ls += e;
    }
    red[t] = ls;
    __syncthreads();
    for (int o = 128; o > 0; o >>= 1) {
        if (t < o) red[t] += red[t + o];
        __syncthreads();
    }
    float inv = 1.f / red[0];
    __syncthreads();

    int part = t >> 5, i = t & 31;
    float acc = 0.f;
    for (int j = part; j < Lk; j += 8)
        acc += sc[j] * V[(size_t)j * D + h * HD + i];
    vout[part][i] = acc;
    __syncthreads();
    if (t < HD) {
        float a = 0.f;
        #pragma unroll
        for (int p = 0; p < 8; p++) a += vout[p][t];
        O[(size_t)l * D + h * HD + t] = a * inv;
    }
}

// ---------------------------------------------------------------------------
// GroupNorm stats over fp32 X [L, FF]: one block per group (32 ch x L).
// ---------------------------------------------------------------------------
__global__ __launch_bounds__(256) void gn_stats_kernel(
    const float* __restrict__ X, float* __restrict__ st)
{
    int g = blockIdx.x, t = threadIdx.x;
    int c = g * 32 + (t & 31);
    float s = 0.f, sq = 0.f;
    for (int l = (t >> 5); l < L; l += 8) {
        float v = X[(size_t)l * FF + c];
        s += v; sq += v * v;
    }
    __shared__ float rs[256], rq[256];
    rs[t] = s; rq[t] = sq;
    __syncthreads();
    for (int o = 128; o > 0; o >>= 1) {
        if (t < o) { rs[t] += rs[t + o]; rq[t] += rq[t + o]; }
        __syncthreads();
    }
    if (t == 0) {
        float n = (float)(L * 32);
        float mean = rs[0] / n;
        float var  = rq[0] / n - mean * mean;
        st[g * 2]     = mean;
        st[g * 2 + 1] = rsqrtf(var + 1e-5f);
    }
}

// GN normalize + exact GELU, elementwise [L,FF] fp32 -> fp32.
__global__ __launch_bounds__(256) void gn_gelu_kernel(
    const float* __restrict__ X, const float* __restrict__ st,
    const float* __restrict__ gg, const float* __restrict__ gb,
    float* __restrict__ Y)
{
    size_t idx = (size_t)blockIdx.x * 256 + threadIdx.x;
    int c = (int)(idx & (FF - 1));
    int g = c >> 5;
    float v = (X[idx] - st[g * 2]) * st[g * 2 + 1] * gg[c] + gb[c];
    Y[idx] = 0.5f * v * (1.f + erff(v * 0.70710678118654752f));
}

// Naive depthwise 5x5 conv (cross-correlation), padding 2, fp32.
__global__ __launch_bounds__(256) void dwconv_naive(
    const float* __restrict__ Y, const float* __restrict__ Kw,
    float* __restrict__ Out)
{
    int l = blockIdx.x;
    int h = l / WWW, w = l % WWW;
    int t = threadIdx.x;
    for (int u = 0; u < FF / 256; u++) {
        int c = u * 256 + t;
        float acc = 0.f;
        for (int ky = 0; ky < 5; ky++) {
            int hy = h + ky - 2;
            if (hy < 0 || hy >= HH) continue;
            for (int kx = 0; kx < 5; kx++) {
                int wx = w + kx - 2;
                if (wx < 0 || wx >= WWW) continue;
                acc += Y[(size_t)(hy * WWW + wx) * FF + c] * Kw[c * 25 + ky * 5 + kx];
            }
        }
        Out[(size_t)l * FF + c] = acc;
    }
}

// ---------------------------------------------------------------------------
extern "C" void kernel_launch(void* const* d_in, const int* in_sizes, int n_in,
                              void* d_out, int out_size, void* d_ws, size_t ws_size,
                              hipStream_t stream)
{
    (void)in_sizes;
    float* out = (float*)d_out;   // reference output dtype is float32

    if (n_in != 34) {
        diag_kernel<<<(out_size + 255) / 256, 256, 0, stream>>>(out, 2000.f, out_size);
        return;
    }

    // Inputs in setup_inputs() dict order (as documented by the harness).
    const float* tgt    = (const float*)d_in[0];
    const float* gK     = (const float*)d_in[1];
    const float* gV     = (const float*)d_in[2];
    const float* lK     = (const float*)d_in[3];
    const float* lV     = (const float*)d_in[4];
    const float* ln1_g  = (const float*)d_in[5];
    const float* ln1_b  = (const float*)d_in[6];
    const float* ln2_g  = (const float*)d_in[7];
    const float* ln2_b  = (const float*)d_in[8];
    const float* ln3_g  = (const float*)d_in[9];
    const float* ln3_b  = (const float*)d_in[10];
    const float* ln4_g  = (const float*)d_in[11];
    const float* ln4_b  = (const float*)d_in[12];
    const float* sa_Wq  = (const float*)d_in[13];
    const float* sa_bq  = (const float*)d_in[14];
    const float* sa_Wk  = (const float*)d_in[15];
    const float* sa_bk  = (const float*)d_in[16];
    const float* sa_Wv  = (const float*)d_in[17];
    const float* sa_bv  = (const float*)d_in[18];
    const float* sa_Wo  = (const float*)d_in[19];
    const float* sa_bo  = (const float*)d_in[20];
    const float* Wq     = (const float*)d_in[21];
    const float* bq     = (const float*)d_in[22];
    const float* lt_Wo  = (const float*)d_in[23];
    const float* lt_bo  = (const float*)d_in[24];
    const float* st_Wo  = (const float*)d_in[25];
    const float* st_bo  = (const float*)d_in[26];
    const float* W1w    = (const float*)d_in[27];
    const float* b1w    = (const float*)d_in[28];
    const float* gn_g   = (const float*)d_in[29];
    const float* gn_b   = (const float*)d_in[30];
    const float* dw_k   = (const float*)d_in[31];
    const float* W2w    = (const float*)d_in[32];
    const float* b2w    = (const float*)d_in[33];

    // Workspace (fp32): t0..t5 [L,D] + X2 [L,FF] + ST.
    // X1 [L,FF] aliases t0..t3 (dead during stage 3).
    const size_t LD = (size_t)L * D;
    const size_t NEED = (6 * LD + (size_t)L * FF + 64) * 4;
    float* ws = (float*)d_ws;
    float* t0 = ws + 0 * LD;
    float* t1 = ws + 1 * LD;
    float* t2 = ws + 2 * LD;
    float* t3 = ws + 3 * LD;
    float* t4 = ws + 4 * LD;
    float* t5 = ws + 5 * LD;
    float* X1 = t0;
    float* X2 = ws + 6 * LD;
    float* ST = X2 + (size_t)L * FF;

    if (ws_size < NEED) {
        int wsMiB = (int)(ws_size >> 20); if (wsMiB > 63) wsMiB = 63;
        diag_kernel<<<(out_size + 255) / 256, 256, 0, stream>>>(out, 64.f + (float)wsMiB, out_size);
        return;
    }

    const float scale = 0.17677669529663687f;  // 1/sqrt(32)
    dim3 blk2(16, 16);
    dim3 gLD((L + 15) / 16, (D + 15) / 16);
    dim3 gLF((L + 15) / 16, (FF + 15) / 16);

    // ---- stage 1: self attention ----
    ln_kernel<<<L, 256, 0, stream>>>(tgt, nullptr, ln1_g, ln1_b, t0);
    gemm_naive<<<gLD, blk2, 0, stream>>>(t0, sa_Wq, sa_bq, nullptr, t1, L, D, D);
    gemm_naive<<<gLD, blk2, 0, stream>>>(t0, sa_Wk, sa_bk, nullptr, t2, L, D, D);
    gemm_naive<<<gLD, blk2, 0, stream>>>(t0, sa_Wv, sa_bv, nullptr, t3, L, D, D);
    attn_naive<<<dim3(L, NHD), 256, L * sizeof(float), stream>>>(t1, t2, t3, t4, L, scale);
    gemm_naive<<<gLD, blk2, 0, stream>>>(t4, sa_Wo, sa_bo, tgt, t5, L, D, D);   // t5 = tgt + SA

    // ---- stage 2: long-term + short-term cross-attention ----
    ln_kernel<<<L, 256, 0, stream>>>(t5, nullptr, ln2_g, ln2_b, t0);            // curr_V
    gemm_naive<<<gLD, blk2, 0, stream>>>(t0, Wq, bq, nullptr, t1, L, D, D);     // curr_Q = curr_K
    ln_kernel<<<L, 256, 0, stream>>>(t1, lK, ln4_g, ln4_b, t2);                 // k_st
    ln_kernel<<<L, 256, 0, stream>>>(t0, lV, ln4_g, ln4_b, t3);                 // v_st
    attn_naive<<<dim3(L, NHD), 256, 2 * L * sizeof(float), stream>>>(t1, gK, gV, t4, 2 * L, scale);
    gemm_naive<<<gLD, blk2, 0, stream>>>(t4, lt_Wo, lt_bo, t5, t5, L, D, D);    // t5 += lt
    attn_naive<<<dim3(L, NHD), 256, L * sizeof(float), stream>>>(t1, t2, t3, t4, L, scale);
    gemm_naive<<<gLD, blk2, 0, stream>>>(t4, st_Wo, st_bo, t5, t5, L, D, D);    // t5 += st

    // ---- stage 3: FFN with GN + GELU + depthwise conv ----
    ln_kernel<<<L, 256, 0, stream>>>(t5, nullptr, ln3_g, ln3_b, t4);            // ln3 (outside X1)
    gemm_naive<<<gLF, blk2, 0, stream>>>(t4, W1w, b1w, nullptr, X1, L, FF, D);
    gn_stats_kernel<<<32, 256, 0, stream>>>(X1, ST);
    gn_gelu_kernel<<<(L * FF) / 256, 256, 0, stream>>>(X1, ST, gn_g, gn_b, X2);
    dwconv_naive<<<L, 256, 0, stream>>>(X2, dw_k, X1);
    gemm_naive<<<gLD, blk2, 0, stream>>>(X1, W2w, b2w, t5, out, L, D, FF);      // out = t5 + FFN (fp32!)
}

// Round 12
// 1747.700 us; speedup vs baseline: 5.4782x; 5.4782x over previous
//
#include <hip/hip_runtime.h>
#include <hip/hip_bf16.h>

#define L   2304
#define D   256
#define NHD 8
#define HD  32
#define FF  1024
#define HH  48
#define WWW 48

#define QT  32    // queries per attention block
#define KT  128   // keys per chunk
#define HDP 36    // HD padded (+4, float4-aligned, breaks stride-32 bank aliasing)
#define KTP 136   // KT padded (+8)

// Diagnostic: fill output with a constant (decodable from reported absmax).
__global__ __launch_bounds__(256) void diag_kernel(float* __restrict__ out, float c, int n)
{
    int i = blockIdx.x * 256 + threadIdx.x;
    if (i < n) out[i] = c;
}

// ---------------------------------------------------------------------------
// LayerNorm over D=256, fp32. One block per row; tree reduction.
// ---------------------------------------------------------------------------
__global__ __launch_bounds__(256) void ln_kernel(
    const float* __restrict__ inA, const float* __restrict__ inB,
    const float* __restrict__ g, const float* __restrict__ b,
    float* __restrict__ out)
{
    int row = blockIdx.x, t = threadIdx.x;
    size_t idx = (size_t)row * D + t;
    float v = inA[idx];
    if (inB) v += inB[idx];
    __shared__ float rs[256], rq[256];
    rs[t] = v; rq[t] = v * v;
    __syncthreads();
    for (int o = 128; o > 0; o >>= 1) {
        if (t < o) { rs[t] += rs[t + o]; rq[t] += rq[t + o]; }
        __syncthreads();
    }
    float mean = rs[0] * (1.f / D);
    float var  = rq[0] * (1.f / D) - mean * mean;
    float rstd = rsqrtf(var + 1e-5f);
    out[idx] = (v - mean) * rstd * g[t] + b[t];
}

// ---------------------------------------------------------------------------
// Tiled GEMM: C[M,N] = A[M,K] @ W[N,K]^T + bias (+res). 64x64 tile,
// K-tiles of 16, 4x4 per thread (16x16 threads). LDS transposed + padded.
// res may alias out (per-thread same idx, read before write).
// ---------------------------------------------------------------------------
__global__ __launch_bounds__(256) void gemm_tiled(
    const float* __restrict__ A, const float* __restrict__ W,
    const float* __restrict__ bias, const float* res, float* out,
    int M, int N, int K)
{
    __shared__ float As[16][68];
    __shared__ float Ws[16][68];
    int t = threadIdx.x;
    int tx = t & 15, ty = t >> 4;
    int m0 = blockIdx.x * 64, n0 = blockIdx.y * 64;
    int lr = t >> 2, lg = t & 3;
    float acc[4][4] = {{0.f}};
    const float* ap = A + (size_t)(m0 + lr) * K + lg * 4;
    const float* wp = W + (size_t)(n0 + lr) * K + lg * 4;
    for (int k0 = 0; k0 < K; k0 += 16) {
        float4 a4 = *reinterpret_cast<const float4*>(ap + k0);
        float4 w4 = *reinterpret_cast<const float4*>(wp + k0);
        __syncthreads();
        As[lg*4+0][lr] = a4.x;
        As[lg*4+1][lr] = a4.y;
        As[lg*4+2][lr] = a4.z;
        As[lg*4+3][lr] = a4.w;
        Ws[lg*4+0][lr] = w4.x;
        Ws[lg*4+1][lr] = w4.y;
        Ws[lg*4+2][lr] = w4.z;
        Ws[lg*4+3][lr] = w4.w;
        __syncthreads();
        #pragma unroll
        for (int kk = 0; kk < 16; kk++) {
            float4 av = *reinterpret_cast<const float4*>(&As[kk][ty * 4]);
            float4 bv = *reinterpret_cast<const float4*>(&Ws[kk][tx * 4]);
            acc[0][0] += av.x*bv.x; acc[0][1] += av.x*bv.y; acc[0][2] += av.x*bv.z; acc[0][3] += av.x*bv.w;
            acc[1][0] += av.y*bv.x; acc[1][1] += av.y*bv.y; acc[1][2] += av.y*bv.z; acc[1][3] += av.y*bv.w;
            acc[2][0] += av.z*bv.x; acc[2][1] += av.z*bv.y; acc[2][2] += av.z*bv.z; acc[2][3] += av.z*bv.w;
            acc[3][0] += av.w*bv.x; acc[3][1] += av.w*bv.y; acc[3][2] += av.w*bv.z; acc[3][3] += av.w*bv.w;
        }
    }
    #pragma unroll
    for (int i = 0; i < 4; i++) {
        int r = m0 + ty * 4 + i;
        #pragma unroll
        for (int j = 0; j < 4; j++) {
            int c = n0 + tx * 4 + j;
            float v = acc[i][j] + bias[c];
            size_t idx = (size_t)r * N + c;
            if (res) v += res[idx];
            out[idx] = v;
        }
    }
}

// ---------------------------------------------------------------------------
// Tiled flash-style attention, fp32. Grid (L/QT, NH), 256 threads.
// Thread t owns query row q=t>>3 within the tile, lane-group g=t&7.
// S phase: each thread computes 16 scores (j = g + 8*jj, bank-conflict-free).
// Online softmax per row via 3 shfl_xor among the aligned 8-lane group.
// PV phase: thread accumulates O[q][g*4..+3] in a float4.
// LDS ~59 KB -> 2 blocks/CU.
// ---------------------------------------------------------------------------
__global__ __launch_bounds__(256) void attn_tiled(
    const float* __restrict__ Q, const float* __restrict__ K,
    const float* __restrict__ V, float* __restrict__ O,
    int Lk, float scale)
{
    __shared__ float Qs[QT][HDP];
    __shared__ float Ks[KT][HDP];
    __shared__ float Vs[KT][HDP];
    __shared__ float Ss[QT][KTP];

    int t = threadIdx.x;
    int h = blockIdx.y;
    int q0 = blockIdx.x * QT;
    int q = t >> 3;            // 0..31
    int g = t & 7;             // 0..7

    // Stage Q tile (scaled): 1024 floats, 1 float4/thread, coalesced.
    {
        int qq = t >> 3, i4 = t & 7;
        float4 v = *reinterpret_cast<const float4*>(Q + (size_t)(q0 + qq) * D + h * HD + i4 * 4);
        Qs[qq][i4*4+0] = v.x * scale;
        Qs[qq][i4*4+1] = v.y * scale;
        Qs[qq][i4*4+2] = v.z * scale;
        Qs[qq][i4*4+3] = v.w * scale;
    }

    float m_r = -1e30f, l_r = 0.f;
    float4 acc = make_float4(0.f, 0.f, 0.f, 0.f);

    for (int k0 = 0; k0 < Lk; k0 += KT) {
        // Prefetch K/V chunk into registers (4 float4 each).
        float4 kr[4], vr[4];
        #pragma unroll
        for (int u = 0; u < 4; u++) {
            int F = u * 256 + t;          // float4 index 0..1023
            int j = F >> 3, i4 = F & 7;
            kr[u] = *reinterpret_cast<const float4*>(K + (size_t)(k0 + j) * D + h * HD + i4 * 4);
            vr[u] = *reinterpret_cast<const float4*>(V + (size_t)(k0 + j) * D + h * HD + i4 * 4);
        }
        __syncthreads();   // prev iteration's consumers done
        #pragma unroll
        for (int u = 0; u < 4; u++) {
            int F = u * 256 + t;
            int j = F >> 3, i4 = F & 7;
            *reinterpret_cast<float4*>(&Ks[j][i4*4]) = kr[u];
            *reinterpret_cast<float4*>(&Vs[j][i4*4]) = vr[u];
        }
        __syncthreads();

        // --- S = Qs @ Ks^T for 16 keys per thread ---
        float s[16];
        #pragma unroll
        for (int jj = 0; jj < 16; jj++) s[jj] = 0.f;
        #pragma unroll
        for (int i4 = 0; i4 < 8; i4++) {
            float4 qv = *reinterpret_cast<const float4*>(&Qs[q][i4*4]);
            #pragma unroll
            for (int jj = 0; jj < 16; jj++) {
                float4 kv = *reinterpret_cast<const float4*>(&Ks[g + 8*jj][i4*4]);
                s[jj] += qv.x*kv.x + qv.y*kv.y + qv.z*kv.z + qv.w*kv.w;
            }
        }

        // --- online softmax (8-lane group per row) ---
        float cm = s[0];
        #pragma unroll
        for (int jj = 1; jj < 16; jj++) cm = fmaxf(cm, s[jj]);
        cm = fmaxf(cm, __shfl_xor(cm, 1));
        cm = fmaxf(cm, __shfl_xor(cm, 2));
        cm = fmaxf(cm, __shfl_xor(cm, 4));
        float mnew = fmaxf(m_r, cm);
        float alpha = __expf(m_r - mnew);
        float ls = 0.f;
        #pragma unroll
        for (int jj = 0; jj < 16; jj++) {
            float p = __expf(s[jj] - mnew);
            Ss[q][g + 8*jj] = p;
            ls += p;
        }
        ls += __shfl_xor(ls, 1);
        ls += __shfl_xor(ls, 2);
        ls += __shfl_xor(ls, 4);
        l_r = l_r * alpha + ls;
        m_r = mnew;
        acc.x *= alpha; acc.y *= alpha; acc.z *= alpha; acc.w *= alpha;
        __syncthreads();   // Ss visible to full block (conservative)

        // --- PV: acc[q][g*4..+3] += P-row . V-cols ---
        #pragma unroll
        for (int j4 = 0; j4 < KT / 4; j4++) {
            float4 p4 = *reinterpret_cast<const float4*>(&Ss[q][j4*4]);
            float4 v0 = *reinterpret_cast<const float4*>(&Vs[j4*4+0][g*4]);
            float4 v1 = *reinterpret_cast<const float4*>(&Vs[j4*4+1][g*4]);
            float4 v2 = *reinterpret_cast<const float4*>(&Vs[j4*4+2][g*4]);
            float4 v3 = *reinterpret_cast<const float4*>(&Vs[j4*4+3][g*4]);
            acc.x += p4.x*v0.x + p4.y*v1.x + p4.z*v2.x + p4.w*v3.x;
            acc.y += p4.x*v0.y + p4.y*v1.y + p4.z*v2.y + p4.w*v3.y;
            acc.z += p4.x*v0.z + p4.y*v1.z + p4.z*v2.z + p4.w*v3.z;
            acc.w += p4.x*v0.w + p4.y*v1.w + p4.z*v2.w + p4.w*v3.w;
        }
    }

    float inv = 1.f / l_r;
    float4 o4 = make_float4(acc.x*inv, acc.y*inv, acc.z*inv, acc.w*inv);
    *reinterpret_cast<float4*>(O + (size_t)(q0 + q) * D + h * HD + g * 4) = o4;
}

// ---------------------------------------------------------------------------
// GroupNorm stats over fp32 X [L, FF]: one block per group (32 ch x L).
// ---------------------------------------------------------------------------
__global__ __launch_bounds__(256) void gn_stats_kernel(
    const float* __restrict__ X, float* __restrict__ st)
{
    int g = blockIdx.x, t = threadIdx.x;
    int c = g * 32 + (t & 31);
    float s = 0.f, sq = 0.f;
    for (int l = (t >> 5); l < L; l += 8) {
        float v = X[(size_t)l * FF + c];
        s += v; sq += v * v;
    }
    __shared__ float rs[256], rq[256];
    rs[t] = s; rq[t] = sq;
    __syncthreads();
    for (int o = 128; o > 0; o >>= 1) {
        if (t < o) { rs[t] += rs[t + o]; rq[t] += rq[t + o]; }
        __syncthreads();
    }
    if (t == 0) {
        float n = (float)(L * 32);
        float mean = rs[0] / n;
        float var  = rq[0] / n - mean * mean;
        st[g * 2]     = mean;
        st[g * 2 + 1] = rsqrtf(var + 1e-5f);
    }
}

// GN normalize + exact GELU, elementwise [L,FF] fp32 -> fp32.
__global__ __launch_bounds__(256) void gn_gelu_kernel(
    const float* __restrict__ X, const float* __restrict__ st,
    const float* __restrict__ gg, const float* __restrict__ gb,
    float* __restrict__ Y)
{
    size_t idx = (size_t)blockIdx.x * 256 + threadIdx.x;
    int c = (int)(idx & (FF - 1));
    int g = c >> 5;
    float v = (X[idx] - st[g * 2]) * st[g * 2 + 1] * gg[c] + gb[c];
    Y[idx] = 0.5f * v * (1.f + erff(v * 0.70710678118654752f));
}

// Naive depthwise 5x5 conv (cross-correlation), padding 2, fp32.
__global__ __launch_bounds__(256) void dwconv_naive(
    const float* __restrict__ Y, const float* __restrict__ Kw,
    float* __restrict__ Out)
{
    int l = blockIdx.x;
    int h = l / WWW, w = l % WWW;
    int t = threadIdx.x;
    for (int u = 0; u < FF / 256; u++) {
        int c = u * 256 + t;
        float acc = 0.f;
        for (int ky = 0; ky < 5; ky++) {
            int hy = h + ky - 2;
            if (hy < 0 || hy >= HH) continue;
            for (int kx = 0; kx < 5; kx++) {
                int wx = w + kx - 2;
                if (wx < 0 || wx >= WWW) continue;
                acc += Y[(size_t)(hy * WWW + wx) * FF + c] * Kw[c * 25 + ky * 5 + kx];
            }
        }
        Out[(size_t)l * FF + c] = acc;
    }
}

// ---------------------------------------------------------------------------
extern "C" void kernel_launch(void* const* d_in, const int* in_sizes, int n_in,
                              void* d_out, int out_size, void* d_ws, size_t ws_size,
                              hipStream_t stream)
{
    (void)in_sizes;
    float* out = (float*)d_out;   // reference output dtype is float32

    if (n_in != 34) {
        diag_kernel<<<(out_size + 255) / 256, 256, 0, stream>>>(out, 2000.f, out_size);
        return;
    }

    const float* tgt    = (const float*)d_in[0];
    const float* gK     = (const float*)d_in[1];
    const float* gV     = (const float*)d_in[2];
    const float* lK     = (const float*)d_in[3];
    const float* lV     = (const float*)d_in[4];
    const float* ln1_g  = (const float*)d_in[5];
    const float* ln1_b  = (const float*)d_in[6];
    const float* ln2_g  = (const float*)d_in[7];
    const float* ln2_b  = (const float*)d_in[8];
    const float* ln3_g  = (const float*)d_in[9];
    const float* ln3_b  = (const float*)d_in[10];
    const float* ln4_g  = (const float*)d_in[11];
    const float* ln4_b  = (const float*)d_in[12];
    const float* sa_Wq  = (const float*)d_in[13];
    const float* sa_bq  = (const float*)d_in[14];
    const float* sa_Wk  = (const float*)d_in[15];
    const float* sa_bk  = (const float*)d_in[16];
    const float* sa_Wv  = (const float*)d_in[17];
    const float* sa_bv  = (const float*)d_in[18];
    const float* sa_Wo  = (const float*)d_in[19];
    const float* sa_bo  = (const float*)d_in[20];
    const float* Wq     = (const float*)d_in[21];
    const float* bq     = (const float*)d_in[22];
    const float* lt_Wo  = (const float*)d_in[23];
    const float* lt_bo  = (const float*)d_in[24];
    const float* st_Wo  = (const float*)d_in[25];
    const float* st_bo  = (const float*)d_in[26];
    const float* W1w    = (const float*)d_in[27];
    const float* b1w    = (const float*)d_in[28];
    const float* gn_g   = (const float*)d_in[29];
    const float* gn_b   = (const float*)d_in[30];
    const float* dw_k   = (const float*)d_in[31];
    const float* W2w    = (const float*)d_in[32];
    const float* b2w    = (const float*)d_in[33];

    // Workspace (fp32): t0..t5 [L,D] + X2 [L,FF] + ST.
    const size_t LD = (size_t)L * D;
    const size_t NEED = (6 * LD + (size_t)L * FF + 64) * 4;
    float* ws = (float*)d_ws;
    float* t0 = ws + 0 * LD;
    float* t1 = ws + 1 * LD;
    float* t2 = ws + 2 * LD;
    float* t3 = ws + 3 * LD;
    float* t4 = ws + 4 * LD;
    float* t5 = ws + 5 * LD;
    float* X1 = t0;                   // [L,FF], spans t0..t3 (dead in stage 3)
    float* X2 = ws + 6 * LD;          // [L,FF]
    float* ST = X2 + (size_t)L * FF;  // 64 floats

    if (ws_size < NEED) {
        int wsMiB = (int)(ws_size >> 20); if (wsMiB > 63) wsMiB = 63;
        diag_kernel<<<(out_size + 255) / 256, 256, 0, stream>>>(out, 64.f + (float)wsMiB, out_size);
        return;
    }

    const float scale = 0.17677669529663687f;  // 1/sqrt(32)
    dim3 gDD(L / 64, D / 64);         // (36, 4)
    dim3 gDF(L / 64, FF / 64);        // (36, 16)
    dim3 gAT(L / QT, NHD);            // (72, 8)

    // ---- stage 1: self attention ----
    ln_kernel<<<L, 256, 0, stream>>>(tgt, nullptr, ln1_g, ln1_b, t0);
    gemm_tiled<<<gDD, 256, 0, stream>>>(t0, sa_Wq, sa_bq, nullptr, t1, L, D, D);
    gemm_tiled<<<gDD, 256, 0, stream>>>(t0, sa_Wk, sa_bk, nullptr, t2, L, D, D);
    gemm_tiled<<<gDD, 256, 0, stream>>>(t0, sa_Wv, sa_bv, nullptr, t3, L, D, D);
    attn_tiled<<<gAT, 256, 0, stream>>>(t1, t2, t3, t4, L, scale);
    gemm_tiled<<<gDD, 256, 0, stream>>>(t4, sa_Wo, sa_bo, tgt, t5, L, D, D);    // t5 = tgt + SA

    // ---- stage 2: long-term + short-term cross-attention ----
    ln_kernel<<<L, 256, 0, stream>>>(t5, nullptr, ln2_g, ln2_b, t0);            // curr_V
    gemm_tiled<<<gDD, 256, 0, stream>>>(t0, Wq, bq, nullptr, t1, L, D, D);      // curr_Q = curr_K
    ln_kernel<<<L, 256, 0, stream>>>(t1, lK, ln4_g, ln4_b, t2);                 // k_st
    ln_kernel<<<L, 256, 0, stream>>>(t0, lV, ln4_g, ln4_b, t3);                 // v_st
    attn_tiled<<<gAT, 256, 0, stream>>>(t1, gK, gV, t4, 2 * L, scale);
    gemm_tiled<<<gDD, 256, 0, stream>>>(t4, lt_Wo, lt_bo, t5, t5, L, D, D);     // t5 += lt
    attn_tiled<<<gAT, 256, 0, stream>>>(t1, t2, t3, t4, L, scale);
    gemm_tiled<<<gDD, 256, 0, stream>>>(t4, st_Wo, st_bo, t5, t5, L, D, D);     // t5 += st

    // ---- stage 3: FFN with GN + GELU + depthwise conv ----
    ln_kernel<<<L, 256, 0, stream>>>(t5, nullptr, ln3_g, ln3_b, t4);            // ln3 (outside X1)
    gemm_tiled<<<gDF, 256, 0, stream>>>(t4, W1w, b1w, nullptr, X1, L, FF, D);
    gn_stats_kernel<<<32, 256, 0, stream>>>(X1, ST);
    gn_gelu_kernel<<<(L * FF) / 256, 256, 0, stream>>>(X1, ST, gn_g, gn_b, X2);
    dwconv_naive<<<L, 256, 0, stream>>>(X2, dw_k, X1);
    gemm_tiled<<<gDD, 256, 0, stream>>>(X1, W2w, b2w, t5, out, L, D, FF);       // out = t5 + FFN
}

// Round 13
// 733.678 us; speedup vs baseline: 13.0496x; 2.3821x over previous
//
#include <hip/hip_runtime.h>
#include <hip/hip_bf16.h>

#define L   2304
#define D   256
#define NHD 8
#define HD  32
#define FF  1024
#define HH  48
#define WWW 48

typedef unsigned short bfraw;
typedef __attribute__((ext_vector_type(8))) short s8v;   // 8 bf16 = 4 VGPRs
typedef __attribute__((ext_vector_type(4))) float f4v;   // MFMA C/D frag

__device__ __forceinline__ bfraw f2b(float x) {
    __hip_bfloat16 h = __float2bfloat16(x);
    return __builtin_bit_cast(bfraw, h);
}

// Diagnostic: fill output with a constant (decodable from reported absmax).
__global__ __launch_bounds__(256) void diag_kernel(float* __restrict__ out, float c, int n)
{
    int i = blockIdx.x * 256 + threadIdx.x;
    if (i < n) out[i] = c;
}

// ---------------------------------------------------------------------------
// LayerNorm over D=256, fp32. One block per row; tree reduction.
// ---------------------------------------------------------------------------
__global__ __launch_bounds__(256) void ln_kernel(
    const float* __restrict__ inA, const float* __restrict__ inB,
    const float* __restrict__ g, const float* __restrict__ b,
    float* __restrict__ out)
{
    int row = blockIdx.x, t = threadIdx.x;
    size_t idx = (size_t)row * D + t;
    float v = inA[idx];
    if (inB) v += inB[idx];
    __shared__ float rs[256], rq[256];
    rs[t] = v; rq[t] = v * v;
    __syncthreads();
    for (int o = 128; o > 0; o >>= 1) {
        if (t < o) { rs[t] += rs[t + o]; rq[t] += rq[t + o]; }
        __syncthreads();
    }
    float mean = rs[0] * (1.f / D);
    float var  = rq[0] * (1.f / D) - mean * mean;
    float rstd = rsqrtf(var + 1e-5f);
    out[idx] = (v - mean) * rstd * g[t] + b[t];
}

// ---------------------------------------------------------------------------
// Tiled fp32 GEMM: C[M,N] = A[M,K] @ W[N,K]^T + bias (+res). 64x64 tile.
// ---------------------------------------------------------------------------
__global__ __launch_bounds__(256) void gemm_tiled(
    const float* __restrict__ A, const float* __restrict__ W,
    const float* __restrict__ bias, const float* res, float* out,
    int M, int N, int K)
{
    __shared__ float As[16][68];
    __shared__ float Ws[16][68];
    int t = threadIdx.x;
    int tx = t & 15, ty = t >> 4;
    int m0 = blockIdx.x * 64, n0 = blockIdx.y * 64;
    int lr = t >> 2, lg = t & 3;
    float acc[4][4] = {{0.f}};
    const float* ap = A + (size_t)(m0 + lr) * K + lg * 4;
    const float* wp = W + (size_t)(n0 + lr) * K + lg * 4;
    for (int k0 = 0; k0 < K; k0 += 16) {
        float4 a4 = *reinterpret_cast<const float4*>(ap + k0);
        float4 w4 = *reinterpret_cast<const float4*>(wp + k0);
        __syncthreads();
        As[lg*4+0][lr] = a4.x; As[lg*4+1][lr] = a4.y;
        As[lg*4+2][lr] = a4.z; As[lg*4+3][lr] = a4.w;
        Ws[lg*4+0][lr] = w4.x; Ws[lg*4+1][lr] = w4.y;
        Ws[lg*4+2][lr] = w4.z; Ws[lg*4+3][lr] = w4.w;
        __syncthreads();
        #pragma unroll
        for (int kk = 0; kk < 16; kk++) {
            float4 av = *reinterpret_cast<const float4*>(&As[kk][ty * 4]);
            float4 bv = *reinterpret_cast<const float4*>(&Ws[kk][tx * 4]);
            acc[0][0] += av.x*bv.x; acc[0][1] += av.x*bv.y; acc[0][2] += av.x*bv.z; acc[0][3] += av.x*bv.w;
            acc[1][0] += av.y*bv.x; acc[1][1] += av.y*bv.y; acc[1][2] += av.y*bv.z; acc[1][3] += av.y*bv.w;
            acc[2][0] += av.z*bv.x; acc[2][1] += av.z*bv.y; acc[2][2] += av.z*bv.z; acc[2][3] += av.z*bv.w;
            acc[3][0] += av.w*bv.x; acc[3][1] += av.w*bv.y; acc[3][2] += av.w*bv.z; acc[3][3] += av.w*bv.w;
        }
    }
    #pragma unroll
    for (int i = 0; i < 4; i++) {
        int r = m0 + ty * 4 + i;
        #pragma unroll
        for (int j = 0; j < 4; j++) {
            int c = n0 + tx * 4 + j;
            float v = acc[i][j] + bias[c];
            size_t idx = (size_t)r * N + c;
            if (res) v += res[idx];
            out[idx] = v;
        }
    }
}

// fp32 [n] -> bf16 [n], vectorized (n % 1024 == 0).
__global__ __launch_bounds__(256) void cvt_kernel(
    const float* __restrict__ in, bfraw* __restrict__ out)
{
    size_t i = ((size_t)blockIdx.x * 256 + threadIdx.x) * 4;
    float4 v = *reinterpret_cast<const float4*>(in + i);
    ushort4 o;
    o.x = f2b(v.x); o.y = f2b(v.y); o.z = f2b(v.z); o.w = f2b(v.w);
    *reinterpret_cast<ushort4*>(out + i) = o;
}

// fp32 [N][D] -> bf16 [NH][HD][N] (transposed per head). Grid (N/32, NH).
__global__ __launch_bounds__(256) void cvtT_kernel(
    const float* __restrict__ in, bfraw* __restrict__ out, int N)
{
    __shared__ float Ls[32][33];
    int h = blockIdx.y, n0 = blockIdx.x * 32, t = threadIdx.x;
    int nl = t >> 3, dq = t & 7;
    float4 v = *reinterpret_cast<const float4*>(in + (size_t)(n0 + nl) * D + h * HD + dq * 4);
    Ls[nl][dq*4+0] = v.x; Ls[nl][dq*4+1] = v.y;
    Ls[nl][dq*4+2] = v.z; Ls[nl][dq*4+3] = v.w;
    __syncthreads();
    int dl = t >> 3, nq = t & 7;
    ushort4 o;
    o.x = f2b(Ls[nq*4+0][dl]); o.y = f2b(Ls[nq*4+1][dl]);
    o.z = f2b(Ls[nq*4+2][dl]); o.w = f2b(Ls[nq*4+3][dl]);
    *reinterpret_cast<ushort4*>(out + (size_t)(h * HD + dl) * N + n0 + nq * 4) = o;
}

// ---------------------------------------------------------------------------
// MFMA flash attention. One wave (64 thr) per (16-query tile, head).
// S^T = K.Q^T via mfma_f32_16x16x32_bf16 (K-dim = HD = 32); column-softmax
// (lane&15 = query) with 2 shfl_xor; P^T -> Ps[q][key] LDS round-trip
// (m120-verified layout transform); PV via 4 MFMAs reading Ps/Vt as b128.
// Q/K bf16 row-major [*, D]; V bf16 transposed [NH][HD][Lk]; O fp32 [L][D].
// ---------------------------------------------------------------------------
__global__ __launch_bounds__(64) void attn_mfma(
    const bfraw* __restrict__ Qb, const bfraw* __restrict__ Kb,
    const bfraw* __restrict__ Vt, float* __restrict__ O,
    int Lk, float scale)
{
    __shared__ short Ks[64][32];    // [key][hd]   row 64 B
    __shared__ short Vts[32][72];   // [d][key]    row 144 B (padded, 16-aligned)
    __shared__ short Ps[16][72];    // [q][key]    row 144 B
    int l = threadIdx.x;
    int h = blockIdx.y, q0 = blockIdx.x * 16;
    int lo = l & 15, quad = l >> 4;

    // Q fragment (B operand): lane holds Q[q=lo][hd=quad*8+j]
    s8v qf = *reinterpret_cast<const s8v*>(Qb + (size_t)(q0 + lo) * D + h * HD + quad * 8);

    float m_r = -1e30f, l_r = 0.f;
    f4v o0 = {0.f, 0.f, 0.f, 0.f}, o1 = {0.f, 0.f, 0.f, 0.f};

    for (int k0 = 0; k0 < Lk; k0 += 64) {
        __syncthreads();
        // stage K chunk: 64 keys x 32 hd
        #pragma unroll
        for (int f = 0; f < 4; f++) {
            int idx = f * 64 + l, key = idx >> 2, part = idx & 3;
            s8v kv = *reinterpret_cast<const s8v*>(Kb + (size_t)(k0 + key) * D + h * HD + part * 8);
            *reinterpret_cast<s8v*>(&Ks[key][part * 8]) = kv;
        }
        // stage V^T chunk: 32 d x 64 keys
        #pragma unroll
        for (int f = 0; f < 4; f++) {
            int idx = f * 64 + l, d = idx >> 3, part = idx & 7;
            s8v vv = *reinterpret_cast<const s8v*>(Vt + (size_t)(h * HD + d) * Lk + k0 + part * 8);
            *reinterpret_cast<s8v*>(&Vts[d][part * 8]) = vv;
        }
        __syncthreads();

        // QK: 4 sub-MFMAs (16 keys each). C = S^T[key][q]: row=key, col=q=lo.
        f4v sc4[4];
        #pragma unroll
        for (int s = 0; s < 4; s++) {
            s8v kf = *reinterpret_cast<const s8v*>(&Ks[lo + 16 * s][quad * 8]);
            sc4[s] = __builtin_amdgcn_mfma_f32_16x16x32_bf16(kf, qf, (f4v){0.f,0.f,0.f,0.f}, 0, 0, 0);
        }
        // scale + chunk max over this lane's 16 scores (all of column q=lo)
        float cm = -1e30f;
        #pragma unroll
        for (int s = 0; s < 4; s++)
            #pragma unroll
            for (int r = 0; r < 4; r++) {
                sc4[s][r] *= scale;
                cm = fmaxf(cm, sc4[s][r]);
            }
        cm = fmaxf(cm, __shfl_xor(cm, 16));
        cm = fmaxf(cm, __shfl_xor(cm, 32));
        float mnew = fmaxf(m_r, cm);
        float alpha = __expf(m_r - mnew);
        float ls = 0.f;
        #pragma unroll
        for (int s = 0; s < 4; s++) {
            float p0 = __expf(sc4[s][0] - mnew), p1 = __expf(sc4[s][1] - mnew);
            float p2 = __expf(sc4[s][2] - mnew), p3 = __expf(sc4[s][3] - mnew);
            ls += p0 + p1 + p2 + p3;
            ushort4 pk;
            pk.x = f2b(p0); pk.y = f2b(p1); pk.z = f2b(p2); pk.w = f2b(p3);
            // keys s*16 + quad*4 .. +3, row q=lo
            *reinterpret_cast<ushort4*>(&Ps[lo][s * 16 + quad * 4]) = pk;
        }
        ls += __shfl_xor(ls, 16);
        ls += __shfl_xor(ls, 32);
        l_r = l_r * alpha + ls;
        m_r = mnew;
        // rescale O accumulators: alpha for row q=quad*4+r lives at lane quad*4+r
        #pragma unroll
        for (int r = 0; r < 4; r++) {
            float a = __shfl(alpha, quad * 4 + r);
            o0[r] *= a; o1[r] *= a;
        }
        __syncthreads();
        // PV: A = Ps[q=lo][k=kc*32+quad*8+j], B = Vts[d][same k]; 2 d-halves
        #pragma unroll
        for (int kc = 0; kc < 2; kc++) {
            s8v pf = *reinterpret_cast<const s8v*>(&Ps[lo][kc * 32 + quad * 8]);
            s8v v0 = *reinterpret_cast<const s8v*>(&Vts[lo][kc * 32 + quad * 8]);
            s8v v1 = *reinterpret_cast<const s8v*>(&Vts[16 + lo][kc * 32 + quad * 8]);
            o0 = __builtin_amdgcn_mfma_f32_16x16x32_bf16(pf, v0, o0, 0, 0, 0);
            o1 = __builtin_amdgcn_mfma_f32_16x16x32_bf16(pf, v1, o1, 0, 0, 0);
        }
    }

    float inv_l = 1.f / l_r;
    #pragma unroll
    for (int r = 0; r < 4; r++) {
        float inv = __shfl(inv_l, quad * 4 + r);
        int qg = q0 + quad * 4 + r;
        O[(size_t)qg * D + h * HD + lo]      = o0[r] * inv;
        O[(size_t)qg * D + h * HD + 16 + lo] = o1[r] * inv;
    }
}

// ---------------------------------------------------------------------------
// GroupNorm stats over fp32 X [L, FF]: one block per group (32 ch x L).
// ---------------------------------------------------------------------------
__global__ __launch_bounds__(256) void gn_stats_kernel(
    const float* __restrict__ X, float* __restrict__ st)
{
    int g = blockIdx.x, t = threadIdx.x;
    int c = g * 32 + (t & 31);
    float s = 0.f, sq = 0.f;
    for (int l = (t >> 5); l < L; l += 8) {
        float v = X[(size_t)l * FF + c];
        s += v; sq += v * v;
    }
    __shared__ float rs[256], rq[256];
    rs[t] = s; rq[t] = sq;
    __syncthreads();
    for (int o = 128; o > 0; o >>= 1) {
        if (t < o) { rs[t] += rs[t + o]; rq[t] += rq[t + o]; }
        __syncthreads();
    }
    if (t == 0) {
        float n = (float)(L * 32);
        float mean = rs[0] / n;
        float var  = rq[0] / n - mean * mean;
        st[g * 2]     = mean;
        st[g * 2 + 1] = rsqrtf(var + 1e-5f);
    }
}

// GN normalize + exact GELU, elementwise [L,FF] fp32 -> fp32.
__global__ __launch_bounds__(256) void gn_gelu_kernel(
    const float* __restrict__ X, const float* __restrict__ st,
    const float* __restrict__ gg, const float* __restrict__ gb,
    float* __restrict__ Y)
{
    size_t idx = (size_t)blockIdx.x * 256 + threadIdx.x;
    int c = (int)(idx & (FF - 1));
    int g = c >> 5;
    float v = (X[idx] - st[g * 2]) * st[g * 2 + 1] * gg[c] + gb[c];
    Y[idx] = 0.5f * v * (1.f + erff(v * 0.70710678118654752f));
}

// Naive depthwise 5x5 conv (cross-correlation), padding 2, fp32.
__global__ __launch_bounds__(256) void dwconv_naive(
    const float* __restrict__ Y, const float* __restrict__ Kw,
    float* __restrict__ Out)
{
    int l = blockIdx.x;
    int h = l / WWW, w = l % WWW;
    int t = threadIdx.x;
    for (int u = 0; u < FF / 256; u++) {
        int c = u * 256 + t;
        float acc = 0.f;
        for (int ky = 0; ky < 5; ky++) {
            int hy = h + ky - 2;
            if (hy < 0 || hy >= HH) continue;
            for (int kx = 0; kx < 5; kx++) {
                int wx = w + kx - 2;
                if (wx < 0 || wx >= WWW) continue;
                acc += Y[(size_t)(hy * WWW + wx) * FF + c] * Kw[c * 25 + ky * 5 + kx];
            }
        }
        Out[(size_t)l * FF + c] = acc;
    }
}

// ---------------------------------------------------------------------------
extern "C" void kernel_launch(void* const* d_in, const int* in_sizes, int n_in,
                              void* d_out, int out_size, void* d_ws, size_t ws_size,
                              hipStream_t stream)
{
    (void)in_sizes;
    float* out = (float*)d_out;   // reference output dtype is float32

    if (n_in != 34) {
        diag_kernel<<<(out_size + 255) / 256, 256, 0, stream>>>(out, 2000.f, out_size);
        return;
    }

    const float* tgt    = (const float*)d_in[0];
    const float* gK     = (const float*)d_in[1];
    const float* gV     = (const float*)d_in[2];
    const float* lK     = (const float*)d_in[3];
    const float* lV     = (const float*)d_in[4];
    const float* ln1_g  = (const float*)d_in[5];
    const float* ln1_b  = (const float*)d_in[6];
    const float* ln2_g  = (const float*)d_in[7];
    const float* ln2_b  = (const float*)d_in[8];
    const float* ln3_g  = (const float*)d_in[9];
    const float* ln3_b  = (const float*)d_in[10];
    const float* ln4_g  = (const float*)d_in[11];
    const float* ln4_b  = (const float*)d_in[12];
    const float* sa_Wq  = (const float*)d_in[13];
    const float* sa_bq  = (const float*)d_in[14];
    const float* sa_Wk  = (const float*)d_in[15];
    const float* sa_bk  = (const float*)d_in[16];
    const float* sa_Wv  = (const float*)d_in[17];
    const float* sa_bv  = (const float*)d_in[18];
    const float* sa_Wo  = (const float*)d_in[19];
    const float* sa_bo  = (const float*)d_in[20];
    const float* Wq     = (const float*)d_in[21];
    const float* bq     = (const float*)d_in[22];
    const float* lt_Wo  = (const float*)d_in[23];
    const float* lt_bo  = (const float*)d_in[24];
    const float* st_Wo  = (const float*)d_in[25];
    const float* st_bo  = (const float*)d_in[26];
    const float* W1w    = (const float*)d_in[27];
    const float* b1w    = (const float*)d_in[28];
    const float* gn_g   = (const float*)d_in[29];
    const float* gn_b   = (const float*)d_in[30];
    const float* dw_k   = (const float*)d_in[31];
    const float* W2w    = (const float*)d_in[32];
    const float* b2w    = (const float*)d_in[33];

    // Workspace (fp32): t0..t5 [L,D] + X2 [L,FF] + ST.
    // bf16 attention buffers (qb/kb/vtb) alias X2 (dead until stage 3):
    //   qb [L,D] | kb [2L,D] | vtb [NH][HD][2L]  = 5*LD bf16 <= X2 (9.4 MB).
    const size_t LD = (size_t)L * D;
    const size_t NEED = (6 * LD + (size_t)L * FF + 64) * 4;
    float* ws = (float*)d_ws;
    float* t0 = ws + 0 * LD;
    float* t1 = ws + 1 * LD;
    float* t2 = ws + 2 * LD;
    float* t3 = ws + 3 * LD;
    float* t4 = ws + 4 * LD;
    float* t5 = ws + 5 * LD;
    float* X1 = t0;                   // [L,FF], spans t0..t3 (dead in stage 3)
    float* X2 = ws + 6 * LD;          // [L,FF]
    float* ST = X2 + (size_t)L * FF;  // 64 floats
    bfraw* qb  = (bfraw*)X2;          // L*D bf16
    bfraw* kb  = qb + LD;             // up to 2L*D bf16
    bfraw* vtb = qb + 3 * LD;         // up to 2L*D bf16 (transposed per head)

    if (ws_size < NEED) {
        int wsMiB = (int)(ws_size >> 20); if (wsMiB > 63) wsMiB = 63;
        diag_kernel<<<(out_size + 255) / 256, 256, 0, stream>>>(out, 64.f + (float)wsMiB, out_size);
        return;
    }

    const float scale = 0.17677669529663687f;  // 1/sqrt(32)
    dim3 gDD(L / 64, D / 64);         // (36, 4)
    dim3 gDF(L / 64, FF / 64);        // (36, 16)
    dim3 gAT(L / 16, NHD);            // (144, 8), 64-thread blocks
    int  cvtLD  = (int)(LD / 1024);   // cvt blocks for L*D
    dim3 gT1(L / 32, NHD);            // cvtT for N=L
    dim3 gT2(2 * L / 32, NHD);        // cvtT for N=2L

    // ---- stage 1: self attention ----
    ln_kernel<<<L, 256, 0, stream>>>(tgt, nullptr, ln1_g, ln1_b, t0);
    gemm_tiled<<<gDD, 256, 0, stream>>>(t0, sa_Wq, sa_bq, nullptr, t1, L, D, D);
    gemm_tiled<<<gDD, 256, 0, stream>>>(t0, sa_Wk, sa_bk, nullptr, t2, L, D, D);
    gemm_tiled<<<gDD, 256, 0, stream>>>(t0, sa_Wv, sa_bv, nullptr, t3, L, D, D);
    cvt_kernel<<<cvtLD, 256, 0, stream>>>(t1, qb);
    cvt_kernel<<<cvtLD, 256, 0, stream>>>(t2, kb);
    cvtT_kernel<<<gT1, 256, 0, stream>>>(t3, vtb, L);
    attn_mfma<<<gAT, 64, 0, stream>>>(qb, kb, vtb, t4, L, scale);
    gemm_tiled<<<gDD, 256, 0, stream>>>(t4, sa_Wo, sa_bo, tgt, t5, L, D, D);   // t5 = tgt + SA

    // ---- stage 2: long-term + short-term cross-attention ----
    ln_kernel<<<L, 256, 0, stream>>>(t5, nullptr, ln2_g, ln2_b, t0);           // curr_V
    gemm_tiled<<<gDD, 256, 0, stream>>>(t0, Wq, bq, nullptr, t1, L, D, D);     // curr_Q = curr_K
    ln_kernel<<<L, 256, 0, stream>>>(t1, lK, ln4_g, ln4_b, t2);                // k_st
    ln_kernel<<<L, 256, 0, stream>>>(t0, lV, ln4_g, ln4_b, t3);                // v_st
    cvt_kernel<<<cvtLD, 256, 0, stream>>>(t1, qb);
    cvt_kernel<<<2 * cvtLD, 256, 0, stream>>>(gK, kb);
    cvtT_kernel<<<gT2, 256, 0, stream>>>(gV, vtb, 2 * L);
    attn_mfma<<<gAT, 64, 0, stream>>>(qb, kb, vtb, t4, 2 * L, scale);
    gemm_tiled<<<gDD, 256, 0, stream>>>(t4, lt_Wo, lt_bo, t5, t5, L, D, D);    // t5 += lt
    cvt_kernel<<<cvtLD, 256, 0, stream>>>(t2, kb);
    cvtT_kernel<<<gT1, 256, 0, stream>>>(t3, vtb, L);
    attn_mfma<<<gAT, 64, 0, stream>>>(qb, kb, vtb, t4, L, scale);
    gemm_tiled<<<gDD, 256, 0, stream>>>(t4, st_Wo, st_bo, t5, t5, L, D, D);    // t5 += st

    // ---- stage 3: FFN with GN + GELU + depthwise conv ----
    ln_kernel<<<L, 256, 0, stream>>>(t5, nullptr, ln3_g, ln3_b, t4);           // ln3 (outside X1)
    gemm_tiled<<<gDF, 256, 0, stream>>>(t4, W1w, b1w, nullptr, X1, L, FF, D);
    gn_stats_kernel<<<32, 256, 0, stream>>>(X1, ST);
    gn_gelu_kernel<<<(L * FF) / 256, 256, 0, stream>>>(X1, ST, gn_g, gn_b, X2);
    dwconv_naive<<<L, 256, 0, stream>>>(X2, dw_k, X1);
    gemm_tiled<<<gDD, 256, 0, stream>>>(X1, W2w, b2w, t5, out, L, D, FF);      // out = t5 + FFN
}

// Round 14
// 620.656 us; speedup vs baseline: 15.4260x; 1.1821x over previous
//
#include <hip/hip_runtime.h>
#include <hip/hip_bf16.h>

#define L   2304
#define D   256
#define NHD 8
#define HD  32
#define FF  1024
#define HH  48
#define WWW 48

typedef unsigned short bfraw;
typedef __attribute__((ext_vector_type(8))) short s8v;   // 8 bf16 = 4 VGPRs
typedef __attribute__((ext_vector_type(4))) float f4v;   // MFMA C/D frag

__device__ __forceinline__ bfraw f2b(float x) {
    __hip_bfloat16 h = __float2bfloat16(x);
    return __builtin_bit_cast(bfraw, h);
}

// Diagnostic: fill output with a constant (decodable from reported absmax).
__global__ __launch_bounds__(256) void diag_kernel(float* __restrict__ out, float c, int n)
{
    int i = blockIdx.x * 256 + threadIdx.x;
    if (i < n) out[i] = c;
}

// ---------------------------------------------------------------------------
// LayerNorm over D=256, fp32 (+ optional bf16 secondary output).
// ---------------------------------------------------------------------------
__global__ __launch_bounds__(256) void ln_kernel(
    const float* __restrict__ inA, const float* __restrict__ inB,
    const float* __restrict__ g, const float* __restrict__ b,
    float* __restrict__ out, bfraw* __restrict__ outb)
{
    int row = blockIdx.x, t = threadIdx.x;
    size_t idx = (size_t)row * D + t;
    float v = inA[idx];
    if (inB) v += inB[idx];
    __shared__ float rs[256], rq[256];
    rs[t] = v; rq[t] = v * v;
    __syncthreads();
    for (int o = 128; o > 0; o >>= 1) {
        if (t < o) { rs[t] += rs[t + o]; rq[t] += rq[t + o]; }
        __syncthreads();
    }
    float mean = rs[0] * (1.f / D);
    float var  = rq[0] * (1.f / D) - mean * mean;
    float rstd = rsqrtf(var + 1e-5f);
    float r = (v - mean) * rstd * g[t] + b[t];
    out[idx] = r;
    if (outb) outb[idx] = f2b(r);
}

// ---------------------------------------------------------------------------
// Tiled fp32 GEMM: C[M,N] = A[M,K] @ W[N,K]^T + bias (+res). 64x64 tile.
// Optional bf16 secondary output outb (fuses the cvt pass).
// ---------------------------------------------------------------------------
__global__ __launch_bounds__(256) void gemm_tiled(
    const float* __restrict__ A, const float* __restrict__ W,
    const float* __restrict__ bias, const float* res, float* out,
    bfraw* __restrict__ outb,
    int M, int N, int K)
{
    __shared__ float As[16][68];
    __shared__ float Ws[16][68];
    int t = threadIdx.x;
    int tx = t & 15, ty = t >> 4;
    int m0 = blockIdx.x * 64, n0 = blockIdx.y * 64;
    int lr = t >> 2, lg = t & 3;
    float acc[4][4] = {{0.f}};
    const float* ap = A + (size_t)(m0 + lr) * K + lg * 4;
    const float* wp = W + (size_t)(n0 + lr) * K + lg * 4;
    for (int k0 = 0; k0 < K; k0 += 16) {
        float4 a4 = *reinterpret_cast<const float4*>(ap + k0);
        float4 w4 = *reinterpret_cast<const float4*>(wp + k0);
        __syncthreads();
        As[lg*4+0][lr] = a4.x; As[lg*4+1][lr] = a4.y;
        As[lg*4+2][lr] = a4.z; As[lg*4+3][lr] = a4.w;
        Ws[lg*4+0][lr] = w4.x; Ws[lg*4+1][lr] = w4.y;
        Ws[lg*4+2][lr] = w4.z; Ws[lg*4+3][lr] = w4.w;
        __syncthreads();
        #pragma unroll
        for (int kk = 0; kk < 16; kk++) {
            float4 av = *reinterpret_cast<const float4*>(&As[kk][ty * 4]);
            float4 bv = *reinterpret_cast<const float4*>(&Ws[kk][tx * 4]);
            acc[0][0] += av.x*bv.x; acc[0][1] += av.x*bv.y; acc[0][2] += av.x*bv.z; acc[0][3] += av.x*bv.w;
            acc[1][0] += av.y*bv.x; acc[1][1] += av.y*bv.y; acc[1][2] += av.y*bv.z; acc[1][3] += av.y*bv.w;
            acc[2][0] += av.z*bv.x; acc[2][1] += av.z*bv.y; acc[2][2] += av.z*bv.z; acc[2][3] += av.z*bv.w;
            acc[3][0] += av.w*bv.x; acc[3][1] += av.w*bv.y; acc[3][2] += av.w*bv.z; acc[3][3] += av.w*bv.w;
        }
    }
    #pragma unroll
    for (int i = 0; i < 4; i++) {
        int r = m0 + ty * 4 + i;
        #pragma unroll
        for (int j = 0; j < 4; j++) {
            int c = n0 + tx * 4 + j;
            float v = acc[i][j] + bias[c];
            size_t idx = (size_t)r * N + c;
            if (res) v += res[idx];
            out[idx] = v;
            if (outb) outb[idx] = f2b(v);
        }
    }
}

// fp32 [n] -> bf16 [n], vectorized (n % 1024 == 0).
__global__ __launch_bounds__(256) void cvt_kernel(
    const float* __restrict__ in, bfraw* __restrict__ out)
{
    size_t i = ((size_t)blockIdx.x * 256 + threadIdx.x) * 4;
    float4 v = *reinterpret_cast<const float4*>(in + i);
    ushort4 o;
    o.x = f2b(v.x); o.y = f2b(v.y); o.z = f2b(v.z); o.w = f2b(v.w);
    *reinterpret_cast<ushort4*>(out + i) = o;
}

// fp32 [N][D] -> bf16 [NH][HD][N] (transposed per head). Grid (N/32, NH).
__global__ __launch_bounds__(256) void cvtT_kernel(
    const float* __restrict__ in, bfraw* __restrict__ out, int N)
{
    __shared__ float Ls[32][33];
    int h = blockIdx.y, n0 = blockIdx.x * 32, t = threadIdx.x;
    int nl = t >> 3, dq = t & 7;
    float4 v = *reinterpret_cast<const float4*>(in + (size_t)(n0 + nl) * D + h * HD + dq * 4);
    Ls[nl][dq*4+0] = v.x; Ls[nl][dq*4+1] = v.y;
    Ls[nl][dq*4+2] = v.z; Ls[nl][dq*4+3] = v.w;
    __syncthreads();
    int dl = t >> 3, nq = t & 7;
    ushort4 o;
    o.x = f2b(Ls[nq*4+0][dl]); o.y = f2b(Ls[nq*4+1][dl]);
    o.z = f2b(Ls[nq*4+2][dl]); o.w = f2b(Ls[nq*4+3][dl]);
    *reinterpret_cast<ushort4*>(out + (size_t)(h * HD + dl) * N + n0 + nq * 4) = o;
}

// ---------------------------------------------------------------------------
// MFMA flash attention. One wave per (16-query tile, head). (verified R13)
// ---------------------------------------------------------------------------
__global__ __launch_bounds__(64) void attn_mfma(
    const bfraw* __restrict__ Qb, const bfraw* __restrict__ Kb,
    const bfraw* __restrict__ Vt, float* __restrict__ O,
    int Lk, float scale)
{
    __shared__ short Ks[64][32];
    __shared__ short Vts[32][72];
    __shared__ short Ps[16][72];
    int l = threadIdx.x;
    int h = blockIdx.y, q0 = blockIdx.x * 16;
    int lo = l & 15, quad = l >> 4;

    s8v qf = *reinterpret_cast<const s8v*>(Qb + (size_t)(q0 + lo) * D + h * HD + quad * 8);

    float m_r = -1e30f, l_r = 0.f;
    f4v o0 = {0.f, 0.f, 0.f, 0.f}, o1 = {0.f, 0.f, 0.f, 0.f};

    for (int k0 = 0; k0 < Lk; k0 += 64) {
        __syncthreads();
        #pragma unroll
        for (int f = 0; f < 4; f++) {
            int idx = f * 64 + l, key = idx >> 2, part = idx & 3;
            s8v kv = *reinterpret_cast<const s8v*>(Kb + (size_t)(k0 + key) * D + h * HD + part * 8);
            *reinterpret_cast<s8v*>(&Ks[key][part * 8]) = kv;
        }
        #pragma unroll
        for (int f = 0; f < 4; f++) {
            int idx = f * 64 + l, d = idx >> 3, part = idx & 7;
            s8v vv = *reinterpret_cast<const s8v*>(Vt + (size_t)(h * HD + d) * Lk + k0 + part * 8);
            *reinterpret_cast<s8v*>(&Vts[d][part * 8]) = vv;
        }
        __syncthreads();

        f4v sc4[4];
        #pragma unroll
        for (int s = 0; s < 4; s++) {
            s8v kf = *reinterpret_cast<const s8v*>(&Ks[lo + 16 * s][quad * 8]);
            sc4[s] = __builtin_amdgcn_mfma_f32_16x16x32_bf16(kf, qf, (f4v){0.f,0.f,0.f,0.f}, 0, 0, 0);
        }
        float cm = -1e30f;
        #pragma unroll
        for (int s = 0; s < 4; s++)
            #pragma unroll
            for (int r = 0; r < 4; r++) {
                sc4[s][r] *= scale;
                cm = fmaxf(cm, sc4[s][r]);
            }
        cm = fmaxf(cm, __shfl_xor(cm, 16));
        cm = fmaxf(cm, __shfl_xor(cm, 32));
        float mnew = fmaxf(m_r, cm);
        float alpha = __expf(m_r - mnew);
        float ls = 0.f;
        #pragma unroll
        for (int s = 0; s < 4; s++) {
            float p0 = __expf(sc4[s][0] - mnew), p1 = __expf(sc4[s][1] - mnew);
            float p2 = __expf(sc4[s][2] - mnew), p3 = __expf(sc4[s][3] - mnew);
            ls += p0 + p1 + p2 + p3;
            ushort4 pk;
            pk.x = f2b(p0); pk.y = f2b(p1); pk.z = f2b(p2); pk.w = f2b(p3);
            *reinterpret_cast<ushort4*>(&Ps[lo][s * 16 + quad * 4]) = pk;
        }
        ls += __shfl_xor(ls, 16);
        ls += __shfl_xor(ls, 32);
        l_r = l_r * alpha + ls;
        m_r = mnew;
        #pragma unroll
        for (int r = 0; r < 4; r++) {
            float a = __shfl(alpha, quad * 4 + r);
            o0[r] *= a; o1[r] *= a;
        }
        __syncthreads();
        #pragma unroll
        for (int kc = 0; kc < 2; kc++) {
            s8v pf = *reinterpret_cast<const s8v*>(&Ps[lo][kc * 32 + quad * 8]);
            s8v v0 = *reinterpret_cast<const s8v*>(&Vts[lo][kc * 32 + quad * 8]);
            s8v v1 = *reinterpret_cast<const s8v*>(&Vts[16 + lo][kc * 32 + quad * 8]);
            o0 = __builtin_amdgcn_mfma_f32_16x16x32_bf16(pf, v0, o0, 0, 0, 0);
            o1 = __builtin_amdgcn_mfma_f32_16x16x32_bf16(pf, v1, o1, 0, 0, 0);
        }
    }

    float inv_l = 1.f / l_r;
    #pragma unroll
    for (int r = 0; r < 4; r++) {
        float inv = __shfl(inv_l, quad * 4 + r);
        int qg = q0 + quad * 4 + r;
        O[(size_t)qg * D + h * HD + lo]      = o0[r] * inv;
        O[(size_t)qg * D + h * HD + 16 + lo] = o1[r] * inv;
    }
}

// ---------------------------------------------------------------------------
// GroupNorm stats over fp32 X [L, FF]: one block per group (32 ch x L).
// ---------------------------------------------------------------------------
__global__ __launch_bounds__(256) void gn_stats_kernel(
    const float* __restrict__ X, float* __restrict__ st)
{
    int g = blockIdx.x, t = threadIdx.x;
    int c = g * 32 + (t & 31);
    float s = 0.f, sq = 0.f;
    for (int l = (t >> 5); l < L; l += 8) {
        float v = X[(size_t)l * FF + c];
        s += v; sq += v * v;
    }
    __shared__ float rs[256], rq[256];
    rs[t] = s; rq[t] = sq;
    __syncthreads();
    for (int o = 128; o > 0; o >>= 1) {
        if (t < o) { rs[t] += rs[t + o]; rq[t] += rq[t + o]; }
        __syncthreads();
    }
    if (t == 0) {
        float n = (float)(L * 32);
        float mean = rs[0] / n;
        float var  = rq[0] / n - mean * mean;
        st[g * 2]     = mean;
        st[g * 2 + 1] = rsqrtf(var + 1e-5f);
    }
}

// ---------------------------------------------------------------------------
// Fused GN + exact-GELU + depthwise 5x5 conv. Grid (6,6,16):
// block = 8x8 spatial tile x 64 channels; stage 12x12 halo (GN+GELU applied,
// zero-padded AFTER activation) in LDS (36.9 KB); conv from LDS, write Y.
// Lane owns channel c = t&63 -> coalesced global, conflict-free LDS.
// ---------------------------------------------------------------------------
__global__ __launch_bounds__(256) void gn_gelu_dwconv(
    const float* __restrict__ X, const float* __restrict__ st,
    const float* __restrict__ gg, const float* __restrict__ gb,
    const float* __restrict__ Kw, float* __restrict__ Y)
{
    __shared__ float tile[144][64];
    int h0 = blockIdx.x * 8, w0 = blockIdx.y * 8, c0 = blockIdx.z * 64;
    int t = threadIdx.x;
    int c = t & 63;
    int cg = (c0 + c) >> 5;
    float mu = st[2 * cg], rs = st[2 * cg + 1];
    float ga = gg[c0 + c], be = gb[c0 + c];

    for (int i = t; i < 144 * 64; i += 256) {
        int sp = i >> 6;                       // 0..143 (i&63 == c)
        int hy = h0 + (sp / 12) - 2, wx = w0 + (sp % 12) - 2;
        float v = 0.f;
        if (hy >= 0 && hy < HH && wx >= 0 && wx < WWW) {
            float x = X[(size_t)(hy * WWW + wx) * FF + c0 + c];
            x = (x - mu) * rs * ga + be;
            v = 0.5f * x * (1.f + erff(x * 0.70710678118654752f));
        }
        tile[sp][c] = v;
    }
    float kw[25];
    #pragma unroll
    for (int i = 0; i < 25; i++) kw[i] = Kw[(size_t)(c0 + c) * 25 + i];
    __syncthreads();

    int sgrp = t >> 6;                         // 0..3, 16 outputs each
    for (int s = 0; s < 16; s++) {
        int sp = sgrp * 16 + s;                // 0..63
        int oh = sp >> 3, ow = sp & 7;
        float acc = 0.f;
        #pragma unroll
        for (int ky = 0; ky < 5; ky++)
            #pragma unroll
            for (int kx = 0; kx < 5; kx++)
                acc += tile[(oh + ky) * 12 + ow + kx][c] * kw[ky * 5 + kx];
        Y[(size_t)((h0 + oh) * WWW + w0 + ow) * FF + c0 + c] = acc;
    }
}

// ---------------------------------------------------------------------------
extern "C" void kernel_launch(void* const* d_in, const int* in_sizes, int n_in,
                              void* d_out, int out_size, void* d_ws, size_t ws_size,
                              hipStream_t stream)
{
    (void)in_sizes;
    float* out = (float*)d_out;   // reference output dtype is float32

    if (n_in != 34) {
        diag_kernel<<<(out_size + 255) / 256, 256, 0, stream>>>(out, 2000.f, out_size);
        return;
    }

    const float* tgt    = (const float*)d_in[0];
    const float* gK     = (const float*)d_in[1];
    const float* gV     = (const float*)d_in[2];
    const float* lK     = (const float*)d_in[3];
    const float* lV     = (const float*)d_in[4];
    const float* ln1_g  = (const float*)d_in[5];
    const float* ln1_b  = (const float*)d_in[6];
    const float* ln2_g  = (const float*)d_in[7];
    const float* ln2_b  = (const float*)d_in[8];
    const float* ln3_g  = (const float*)d_in[9];
    const float* ln3_b  = (const float*)d_in[10];
    const float* ln4_g  = (const float*)d_in[11];
    const float* ln4_b  = (const float*)d_in[12];
    const float* sa_Wq  = (const float*)d_in[13];
    const float* sa_bq  = (const float*)d_in[14];
    const float* sa_Wk  = (const float*)d_in[15];
    const float* sa_bk  = (const float*)d_in[16];
    const float* sa_Wv  = (const float*)d_in[17];
    const float* sa_bv  = (const float*)d_in[18];
    const float* sa_Wo  = (const float*)d_in[19];
    const float* sa_bo  = (const float*)d_in[20];
    const float* Wq     = (const float*)d_in[21];
    const float* bq     = (const float*)d_in[22];
    const float* lt_Wo  = (const float*)d_in[23];
    const float* lt_bo  = (const float*)d_in[24];
    const float* st_Wo  = (const float*)d_in[25];
    const float* st_bo  = (const float*)d_in[26];
    const float* W1w    = (const float*)d_in[27];
    const float* b1w    = (const float*)d_in[28];
    const float* gn_g   = (const float*)d_in[29];
    const float* gn_b   = (const float*)d_in[30];
    const float* dw_k   = (const float*)d_in[31];
    const float* W2w    = (const float*)d_in[32];
    const float* b2w    = (const float*)d_in[33];

    // Workspace (fp32): t0..t5 [L,D] + X2 [L,FF] + ST.
    // bf16 attention buffers alias X2 (dead until the stage-3 conv):
    //   qb[LD] | kb1[2LD] | vtb1[2LD] | kb2[LD] | vtb2[LD] = 7*LD bf16 (8.26MB)
    const size_t LD = (size_t)L * D;
    const size_t NEED = (6 * LD + (size_t)L * FF + 64) * 4;
    float* ws = (float*)d_ws;
    float* t0 = ws + 0 * LD;
    float* t1 = ws + 1 * LD;
    float* t2 = ws + 2 * LD;
    float* t3 = ws + 3 * LD;
    float* t4 = ws + 4 * LD;
    float* t5 = ws + 5 * LD;
    float* X1 = t0;                   // [L,FF], spans t0..t3 (dead in stage 3)
    float* X2 = ws + 6 * LD;          // [L,FF]
    float* ST = X2 + (size_t)L * FF;  // 64 floats
    bfraw* qb   = (bfraw*)X2;
    bfraw* kb1  = qb + LD;            // gK bf16 (2L)
    bfraw* vtb1 = qb + 3 * LD;        // gV^T bf16 (2L)
    bfraw* kb2  = qb + 5 * LD;        // self/st K bf16 (L)
    bfraw* vtb2 = qb + 6 * LD;        // self/st V^T bf16 (L)

    if (ws_size < NEED) {
        int wsMiB = (int)(ws_size >> 20); if (wsMiB > 63) wsMiB = 63;
        diag_kernel<<<(out_size + 255) / 256, 256, 0, stream>>>(out, 64.f + (float)wsMiB, out_size);
        return;
    }

    const float scale = 0.17677669529663687f;  // 1/sqrt(32)
    dim3 gDD(L / 64, D / 64);         // (36, 4)
    dim3 gDF(L / 64, FF / 64);        // (36, 16)
    dim3 gAT(L / 16, NHD);            // (144, 8), 64-thread blocks
    int  cvtLD  = (int)(LD / 1024);
    dim3 gT1(L / 32, NHD);
    dim3 gT2(2 * L / 32, NHD);
    dim3 gDW(6, 6, 16);               // fused gn+gelu+dwconv

    // ---- stage 1: self attention ----
    ln_kernel<<<L, 256, 0, stream>>>(tgt, nullptr, ln1_g, ln1_b, t0, nullptr);
    gemm_tiled<<<gDD, 256, 0, stream>>>(t0, sa_Wq, sa_bq, nullptr, t1, qb,  L, D, D);
    gemm_tiled<<<gDD, 256, 0, stream>>>(t0, sa_Wk, sa_bk, nullptr, t2, kb2, L, D, D);
    gemm_tiled<<<gDD, 256, 0, stream>>>(t0, sa_Wv, sa_bv, nullptr, t3, nullptr, L, D, D);
    cvtT_kernel<<<gT1, 256, 0, stream>>>(t3, vtb2, L);
    attn_mfma<<<gAT, 64, 0, stream>>>(qb, kb2, vtb2, t4, L, scale);
    gemm_tiled<<<gDD, 256, 0, stream>>>(t4, sa_Wo, sa_bo, tgt, t5, nullptr, L, D, D); // t5 = tgt + SA

    // ---- stage 2: long-term + short-term cross-attention ----
    ln_kernel<<<L, 256, 0, stream>>>(t5, nullptr, ln2_g, ln2_b, t0, nullptr);          // curr_V
    gemm_tiled<<<gDD, 256, 0, stream>>>(t0, Wq, bq, nullptr, t1, qb, L, D, D);         // curr_Q
    ln_kernel<<<L, 256, 0, stream>>>(t1, lK, ln4_g, ln4_b, t2, kb2);                   // k_st (+bf16)
    ln_kernel<<<L, 256, 0, stream>>>(t0, lV, ln4_g, ln4_b, t3, nullptr);               // v_st
    cvt_kernel<<<2 * cvtLD, 256, 0, stream>>>(gK, kb1);
    cvtT_kernel<<<gT2, 256, 0, stream>>>(gV, vtb1, 2 * L);
    attn_mfma<<<gAT, 64, 0, stream>>>(qb, kb1, vtb1, t4, 2 * L, scale);
    gemm_tiled<<<gDD, 256, 0, stream>>>(t4, lt_Wo, lt_bo, t5, t5, nullptr, L, D, D);   // t5 += lt
    cvtT_kernel<<<gT1, 256, 0, stream>>>(t3, vtb2, L);
    attn_mfma<<<gAT, 64, 0, stream>>>(qb, kb2, vtb2, t4, L, scale);
    gemm_tiled<<<gDD, 256, 0, stream>>>(t4, st_Wo, st_bo, t5, t5, nullptr, L, D, D);   // t5 += st

    // ---- stage 3: FFN with fused GN + GELU + depthwise conv ----
    ln_kernel<<<L, 256, 0, stream>>>(t5, nullptr, ln3_g, ln3_b, t4, nullptr);          // ln3 (outside X1)
    gemm_tiled<<<gDF, 256, 0, stream>>>(t4, W1w, b1w, nullptr, X1, nullptr, L, FF, D);
    gn_stats_kernel<<<32, 256, 0, stream>>>(X1, ST);
    gn_gelu_dwconv<<<gDW, 256, 0, stream>>>(X1, ST, gn_g, gn_b, dw_k, X2);             // X2 = conv out
    gemm_tiled<<<gDD, 256, 0, stream>>>(X2, W2w, b2w, t5, out, nullptr, L, D, FF);     // out = t5 + FFN
}